// Round 3
// baseline (3371.267 us; speedup 1.0000x reference)
//
#include <hip/hip_runtime.h>
#include <hip/hip_bf16.h>
#include <float.h>

// Problem constants
#define BQ    64      // batch
#define CDIM  640     // channels (K)
#define LQ    441     // query descriptors per image
#define NCLS  32      // support classes
#define MS    2205    // support descriptors per class
#define ITILES 7      // 7*64 = 448 padded rows
#define WCHUNK 768    // block j-chunk width (12 waves x 64 cols); 3*768 = 2304
#define NJC3   3
#define NKC    10     // 640/64 k-chunks
#define NEG_INF (-3.0e38f)

// A blob per (b,it): fragment order [kc 10][ks 2][r 4][lane 64] x 16B = 81920 B
#define ABYTES 81920
// B blob per class: [mc3 3][kc 10][ks 2][jf 48][lane 64] x 16B
#define BKC    98304                // per-kc chunk
#define BMC3   (NKC * BKC)          // 983,040 per 768-col chunk
#define BN     (NJC3 * BMC3)        // 2,949,120 per class

typedef __attribute__((ext_vector_type(8))) short short8;
typedef __attribute__((ext_vector_type(4))) float f32x4;

// insert s into sorted (a>=b>=c) keeping top-3: 3 VALU ops via med3
__device__ __forceinline__ void ins3(float s, float& a, float& b, float& c) {
  float na = fmaxf(a, s);
  float nb = __builtin_amdgcn_fmed3f(a, b, s);
  float nc = __builtin_amdgcn_fmed3f(b, c, s);
  a = na; b = nb; c = nc;
}

// ---------------- prep: normalize x1 over C, emit A in MFMA-fragment order ----------------
// granule g (16B) at [bx][kc][g]: g = ks*256 + r*64 + lane; lane = q*16+l15;
// holds A[row = r*16+l15][k = kc*64 + ks*32 + q*8 .. +7]
__global__ __launch_bounds__(256) void prep_q(const float* __restrict__ x1,
                                              char* __restrict__ Abf) {
  const int it = blockIdx.x;   // 0..6
  const int b  = blockIdx.y;   // 0..63
  const int t  = threadIdx.x;
  const int il = t & 63, cg = t >> 6;
  __shared__ float red[4][64];
  __shared__ float rnq[64];
  __shared__ unsigned short tile[64][66];   // [c][i]

  const int i = it * 64 + il;
  float ss = 0.f;
  if (i < LQ) {
    for (int c = cg; c < CDIM; c += 4) {
      float v = x1[((size_t)b * CDIM + c) * LQ + i];
      ss += v * v;
    }
  }
  red[cg][il] = ss;
  __syncthreads();
  if (t < 64) {
    float s = red[0][t] + red[1][t] + red[2][t] + red[3][t];
    rnq[t] = (it * 64 + t < LQ) ? rsqrtf(s) : 0.f;
  }
  __syncthreads();

  int4* gblob = (int4*)(Abf + (size_t)(b * ITILES + it) * ABYTES);
  for (int kc = 0; kc < NKC; ++kc) {
    for (int idx = t; idx < 4096; idx += 256) {
      int cc = idx >> 6, ii = idx & 63;       // consecutive i -> coalesced global read
      int gi = it * 64 + ii;
      float v = 0.f;
      if (gi < LQ) v = x1[((size_t)b * CDIM + kc * 64 + cc) * LQ + gi] * rnq[ii];
      __hip_bfloat16 h = __float2bfloat16(v);
      tile[cc][ii] = *(unsigned short*)&h;
    }
    __syncthreads();
    for (int g = t; g < 512; g += 256) {      // consecutive g -> coalesced 16B writes
      int ks = g >> 8, r = (g >> 6) & 3, ln = g & 63;
      int q = ln >> 4, cl = ln & 15;
      int row = r * 16 + cl, k0 = ks * 32 + q * 8;
      unsigned int u0 = (unsigned int)tile[k0 + 0][row] | ((unsigned int)tile[k0 + 1][row] << 16);
      unsigned int u1 = (unsigned int)tile[k0 + 2][row] | ((unsigned int)tile[k0 + 3][row] << 16);
      unsigned int u2 = (unsigned int)tile[k0 + 4][row] | ((unsigned int)tile[k0 + 5][row] << 16);
      unsigned int u3 = (unsigned int)tile[k0 + 6][row] | ((unsigned int)tile[k0 + 7][row] << 16);
      int4 w; w.x = u0; w.y = u1; w.z = u2; w.w = u3;
      gblob[kc * 512 + g] = w;
    }
    __syncthreads();
  }
}

// ---------------- prep: normalize x2 over C, emit B in MFMA-fragment order (768-col chunks) ----------------
// Bbf[n][mc3] region: per kc chunk [ks 2][jf 48][lane 64] x 16B; granule holds
// B[col = mc3*768 + jf*16 + l15][k = kc*64 + ks*32 + q*8 .. +7]
__global__ __launch_bounds__(256) void prep_s(const float* __restrict__ x2,
                                              char* __restrict__ Bbf) {
  const int jc = blockIdx.x;   // 0..8 (256-col groups)
  const int n  = blockIdx.y;   // 0..31
  const int t  = threadIdx.x;
  const int mc3 = jc / 3, jt3 = jc % 3;
  __shared__ float rns[256];
  __shared__ unsigned short tile[64][266];

  const int j = jc * 256 + t;
  float ss = 0.f;
  if (j < MS) {
    for (int c = 0; c < CDIM; ++c) {
      float v = x2[((size_t)n * CDIM + c) * MS + j];
      ss += v * v;
    }
  }
  rns[t] = (j < MS) ? rsqrtf(ss) : 0.f;
  __syncthreads();

  char* blob = Bbf + ((size_t)n * NJC3 + mc3) * BMC3;
  for (int kc = 0; kc < NKC; ++kc) {
    for (int idx = t; idx < 16384; idx += 256) {
      int cc = idx >> 8, jj = idx & 255;      // consecutive jj -> coalesced global read
      int gj = jc * 256 + jj;
      float v = 0.f;
      if (gj < MS) v = x2[((size_t)n * CDIM + kc * 64 + cc) * MS + gj] * rns[jj];
      __hip_bfloat16 h = __float2bfloat16(v);
      tile[cc][jj] = *(unsigned short*)&h;
    }
    __syncthreads();
    for (int g = t; g < 2048; g += 256) {     // consecutive g -> coalesced 16B writes
      int ks = g >> 10, jf = (g >> 6) & 15, ln = g & 63;
      int qq = ln >> 4, cl = ln & 15;
      int col = jf * 16 + cl, k0 = ks * 32 + qq * 8;
      unsigned int u0 = (unsigned int)tile[k0 + 0][col] | ((unsigned int)tile[k0 + 1][col] << 16);
      unsigned int u1 = (unsigned int)tile[k0 + 2][col] | ((unsigned int)tile[k0 + 3][col] << 16);
      unsigned int u2 = (unsigned int)tile[k0 + 4][col] | ((unsigned int)tile[k0 + 5][col] << 16);
      unsigned int u3 = (unsigned int)tile[k0 + 6][col] | ((unsigned int)tile[k0 + 7][col] << 16);
      int4 w; w.x = u0; w.y = u1; w.z = u2; w.w = u3;
      *(int4*)(blob + (size_t)kc * BKC + (size_t)(ks * 3072 + (jt3 * 16 + jf) * 64 + ln) * 16) = w;
    }
    __syncthreads();
  }
}

// ---------------- main: 768-thread block (12 waves share one 80KB A tile), barrier-free K loop ----------------
// grid 14336: xcd = bid&7 -> classes n = xcd*4 .. +3 for L2 locality.
__global__ __launch_bounds__(768, 3) void gemm_topk(const char* __restrict__ Abf,
                                                    const char* __restrict__ Bbf,
                                                    float* __restrict__ out) {
  const int bid = blockIdx.x;
  const int xcd = bid & 7;
  const int s   = bid >> 3;              // 0..1791
  const int n   = xcd * 4 + s / 448;     // 4 classes per XCD
  const int bx  = s % 448;               // b*7 + it
  const int b   = bx / 7;
  const int t    = threadIdx.x;
  const int lane = t & 63, wave = t >> 6;   // wave 0..11
  const int l15  = lane & 15, q = lane >> 4;

  __shared__ __align__(16) char smem[ABYTES];   // A tile (fragment order); reused as merge aux

  // ---- stage A once: identity copy (blob already in LDS read order) ----
  {
    const int4* gA = (const int4*)(Abf + (size_t)bx * ABYTES);
    int4* sA = (int4*)smem;
    for (int idx = t; idx < 5120; idx += 768) sA[idx] = gA[idx];
  }
  __syncthreads();

  float t3[16][3];
  #pragma unroll
  for (int r = 0; r < 16; ++r) { t3[r][0] = NEG_INF; t3[r][1] = NEG_INF; t3[r][2] = NEG_INF; }

  // B fragment base: this wave's 4 jf granule-columns
  const char* BnB = Bbf + (size_t)n * BN + wave * 4096 + lane * 16;
  const char* As  = smem + lane * 16;

  short8 bcur[2][4], bnxt[2][4];
  #pragma unroll
  for (int ks = 0; ks < 2; ++ks)
    #pragma unroll
    for (int c = 0; c < 4; ++c)
      bcur[ks][c] = *(const short8*)(BnB + ks * 49152 + c * 1024);
  int off = 0;

  for (int mc = 0; mc < NJC3; ++mc) {
    f32x4 acc[4][4];
    #pragma unroll
    for (int r = 0; r < 4; ++r)
      #pragma unroll
      for (int c = 0; c < 4; ++c) acc[r][c] = (f32x4){0.f, 0.f, 0.f, 0.f};

    #pragma unroll 2
    for (int kc = 0; kc < NKC; ++kc) {
      int offn = off + BKC;
      if (offn == BN) offn = 0;             // wrap: harmless re-read of class start
      #pragma unroll
      for (int ks = 0; ks < 2; ++ks)
        #pragma unroll
        for (int c = 0; c < 4; ++c)
          bnxt[ks][c] = *(const short8*)(BnB + offn + ks * 49152 + c * 1024);

      #pragma unroll
      for (int ks = 0; ks < 2; ++ks) {
        short8 af[4];
        #pragma unroll
        for (int r = 0; r < 4; ++r)
          af[r] = *(const short8*)(As + kc * 8192 + ks * 4096 + r * 1024);  // conflict-free b128
        #pragma unroll
        for (int r = 0; r < 4; ++r)
          #pragma unroll
          for (int c = 0; c < 4; ++c)
            acc[r][c] = __builtin_amdgcn_mfma_f32_16x16x32_bf16(af[r], bcur[ks][c], acc[r][c], 0, 0, 0);
      }
      #pragma unroll
      for (int ks = 0; ks < 2; ++ks)
        #pragma unroll
        for (int c = 0; c < 4; ++c) bcur[ks][c] = bnxt[ks][c];
      off = offn;
    }

    // fold this chunk's 64 scores/lane into running top-3
    #pragma unroll
    for (int c = 0; c < 4; ++c) {
      const int jg = mc * WCHUNK + wave * 64 + c * 16 + l15;
      const bool jv = jg < MS;              // mask padded support columns
      #pragma unroll
      for (int r = 0; r < 4; ++r)
        #pragma unroll
        for (int reg = 0; reg < 4; ++reg) {
          float sv = jv ? acc[r][c][reg] : NEG_INF;
          ins3(sv, t3[r * 4 + reg][0], t3[r * 4 + reg][1], t3[r * 4 + reg][2]);
        }
    }
  }

  // ---- intra-wave butterfly merge over the 16 l15-lanes (rows identical within a q-group) ----
  #pragma unroll
  for (int m = 1; m <= 8; m <<= 1) {
    #pragma unroll
    for (int ri = 0; ri < 16; ++ri) {
      float oa = __shfl_xor(t3[ri][0], m, 64);
      float ob = __shfl_xor(t3[ri][1], m, 64);
      float oc = __shfl_xor(t3[ri][2], m, 64);
      ins3(oa, t3[ri][0], t3[ri][1], t3[ri][2]);
      ins3(ob, t3[ri][0], t3[ri][1], t3[ri][2]);
      ins3(oc, t3[ri][0], t3[ri][1], t3[ri][2]);
    }
  }

  __syncthreads();                          // all waves done reading A tile; reuse smem
  float* aux = (float*)smem;                // [64 rows][12 waves][3] = 9216 B
  if (l15 == 0) {
    #pragma unroll
    for (int r = 0; r < 4; ++r)
      #pragma unroll
      for (int reg = 0; reg < 4; ++reg) {
        int row = r * 16 + q * 4 + reg;     // C/D layout: row = quad*4 + reg
        float* p = &aux[(row * 12 + wave) * 3];
        p[0] = t3[r * 4 + reg][0]; p[1] = t3[r * 4 + reg][1]; p[2] = t3[r * 4 + reg][2];
      }
  }
  __syncthreads();
  if (t < 64) {                             // wave 0: final top-3 per row, sum, one atomic
    const float* p = &aux[t * 36];
    float a = p[0], bb = p[1], cc = p[2];
    for (int v = 3; v < 36; ++v) ins3(p[v], a, bb, cc);
    float sum = a + bb + cc;                // padded query rows: all scores 0 -> contributes 0
    for (int offr = 32; offr > 0; offr >>= 1) sum += __shfl_down(sum, offr);
    if (t == 0) atomicAdd(&out[b * NCLS + n], sum);
  }
}

extern "C" void kernel_launch(void* const* d_in, const int* in_sizes, int n_in,
                              void* d_out, int out_size, void* d_ws, size_t ws_size,
                              hipStream_t stream) {
  const float* x1 = (const float*)d_in[0];   // [64, 640, 441] fp32
  const float* x2 = (const float*)d_in[1];   // [32, 640, 2205] fp32
  float* out = (float*)d_out;                // [64, 32] fp32

  // workspace: Abf 36,700,160 B | Bbf 94,371,840 B  (total ~131 MB)
  char* Abf = (char*)d_ws;
  char* Bbf = (char*)d_ws + (size_t)BQ * ITILES * ABYTES;

  hipMemsetAsync(d_out, 0, BQ * NCLS * sizeof(float), stream);
  prep_q<<<dim3(ITILES, BQ), 256, 0, stream>>>(x1, Abf);
  prep_s<<<dim3(9, NCLS), 256, 0, stream>>>(x2, Bbf);
  gemm_topk<<<BQ * ITILES * NCLS, 768, 0, stream>>>(Abf, Bbf, out);
}